// Round 1
// baseline (681.405 us; speedup 1.0000x reference)
//
#include <hip/hip_runtime.h>

typedef __bf16 bf16x8 __attribute__((ext_vector_type(8)));
typedef float f32x4 __attribute__((ext_vector_type(4)));

__device__ __forceinline__ ushort f2b(float f){
  union { float f; unsigned u; } v; v.f = f;
  unsigned r = v.u + 0x7FFFu + ((v.u >> 16) & 1u);
  return (ushort)(r >> 16);
}
__device__ __forceinline__ float b2f(ushort b){
  union { unsigned u; float f; } v; v.u = ((unsigned)b) << 16; return v.f;
}

// ---------------- converts ----------------
__global__ __launch_bounds__(256) void cvt_bf16_k(const float* __restrict__ in,
                                                  ushort* __restrict__ out, int n4){
  int i = blockIdx.x*256 + threadIdx.x;
  if (i < n4){
    f32x4 v = reinterpret_cast<const f32x4*>(in)[i];
    ushort4 o = make_ushort4(f2b(v.x), f2b(v.y), f2b(v.z), f2b(v.w));
    reinterpret_cast<ushort4*>(out)[i] = o;
  }
}

// enc (324x2048) -> bf16 padded to 384x2048 (pad rows zero)
__global__ __launch_bounds__(256) void cvt_enc_k(const float* __restrict__ in,
                                                 ushort* __restrict__ out){
  int i = blockIdx.x*256 + threadIdx.x;   // one float4 per thread
  if (i < 384*2048/4){
    f32x4 v = {0.f,0.f,0.f,0.f};
    if (i < 324*2048/4) v = reinterpret_cast<const f32x4*>(in)[i];
    ushort4 o = make_ushort4(f2b(v.x), f2b(v.y), f2b(v.z), f2b(v.w));
    reinterpret_cast<ushort4*>(out)[i] = o;
  }
}

// W[K][N] fp32 -> Wt[N][K] bf16
__global__ __launch_bounds__(256) void transpose_bf16_k(const float* __restrict__ W,
                                                        ushort* __restrict__ Wt, int K, int N){
  __shared__ float tile[32][33];
  int n0 = blockIdx.x*32, k0 = blockIdx.y*32;
  int tx = threadIdx.x & 31, ty = threadIdx.x >> 5;
  for (int i = ty; i < 32; i += 8) tile[i][tx] = W[(size_t)(k0+i)*N + n0+tx];
  __syncthreads();
  for (int i = ty; i < 32; i += 8) Wt[(size_t)(n0+i)*K + k0+tx] = f2b(tile[tx][i]);
}

// ---------------- GEMM: C[M][N] = A[M][K](bf16,lda) @ Bt[N][K](bf16,ldb) ----------------
// mode 0: bf16 store; mode 1: fp32 + bias[col] + resid; mode 2: fp32 plain
__global__ __launch_bounds__(256) void gemm64(
    const ushort* __restrict__ A, const ushort* __restrict__ Bt,
    int M, int N, int K, int lda, int ldb, int ldo,
    long long sA, long long sB, long long sO,
    float* __restrict__ outF, ushort* __restrict__ outB,
    const float* __restrict__ bias, const float* __restrict__ resid, int mode)
{
  __shared__ ushort As[64][40];
  __shared__ ushort Bs[64][40];
  int ntiles = N >> 6;
  int mt = blockIdx.x / ntiles;
  int nt = blockIdx.x - mt*ntiles;
  int z  = blockIdx.z;
  const ushort* Ab = A + (size_t)z*sA;
  const ushort* Bb = Bt + (size_t)z*sB;
  int t = threadIdx.x;
  int w = t >> 6, l = t & 63;
  int lr = t >> 2, lc = (t & 3) << 3;
  int fr = l & 15, fk = (l >> 4) << 3;
  f32x4 acc[4];
  #pragma unroll
  for (int n = 0; n < 4; ++n) acc[n] = (f32x4){0.f,0.f,0.f,0.f};

  const ushort* Aptr = Ab + (size_t)(mt*64 + lr)*lda + lc;
  const ushort* Bptr = Bb + (size_t)(nt*64 + lr)*ldb + lc;
  for (int k0 = 0; k0 < K; k0 += 32){
    uint4 av = *reinterpret_cast<const uint4*>(Aptr + k0);
    uint4 bv = *reinterpret_cast<const uint4*>(Bptr + k0);
    __syncthreads();
    *reinterpret_cast<uint4*>(&As[lr][lc]) = av;
    *reinterpret_cast<uint4*>(&Bs[lr][lc]) = bv;
    __syncthreads();
    bf16x8 af = *reinterpret_cast<const bf16x8*>(&As[w*16 + fr][fk]);
    #pragma unroll
    for (int n = 0; n < 4; ++n){
      bf16x8 bf = *reinterpret_cast<const bf16x8*>(&Bs[n*16 + fr][fk]);
      acc[n] = __builtin_amdgcn_mfma_f32_16x16x32_bf16(af, bf, acc[n], 0, 0, 0);
    }
  }
  int fq = l >> 4;
  #pragma unroll
  for (int n = 0; n < 4; ++n){
    #pragma unroll
    for (int r = 0; r < 4; ++r){
      int row = mt*64 + w*16 + fq*4 + r;
      int col = nt*64 + n*16 + fr;
      size_t oidx = (size_t)z*sO + (size_t)row*ldo + col;
      float v = acc[n][r];
      if (mode == 0)      outB[oidx] = f2b(v);
      else if (mode == 1) outF[oidx] = v + bias[col] + resid[oidx];
      else                outF[oidx] = v;
    }
  }
}

// ---------------- T_ip[b][k][n] = 0.125 * sum_c text[b,k,c]*ip[b,n,c] ----------------
__global__ __launch_bounds__(64) void tip_k(const float* __restrict__ enc, float* __restrict__ tip){
  int k = blockIdx.x, n = blockIdx.y, b = blockIdx.z;
  const float* text = enc + ((size_t)b*81 + k)*2048;
  const float* ip   = enc + ((size_t)b*81 + 77 + n)*2048;
  int l = threadIdx.x;
  float acc = 0.f;
  for (int c = l; c < 2048; c += 64) acc += text[c]*ip[c];
  for (int off = 32; off > 0; off >>= 1) acc += __shfl_down(acc, off);
  if (l == 0) tip[((size_t)b*77 + k)*4 + n] = acc * 0.125f;
}

// ---------------- softmax over 77 logits + sem = p @ T_ip ----------------
__global__ __launch_bounds__(128) void semsm_k(const float* __restrict__ logits,
    const float* __restrict__ tip, float* __restrict__ sem)
{
  int row = blockIdx.x;           // 0..16383 (b*4096+s)
  int b = row >> 12;
  int t = threadIdx.x;
  __shared__ float ls[77];
  __shared__ float ps[77];
  if (t < 77) ls[t] = logits[(size_t)row*128 + t] * 0.125f;
  __syncthreads();
  float m = -1e30f;
  for (int k = 0; k < 77; ++k) m = fmaxf(m, ls[k]);
  float s = 0.f;
  for (int k = 0; k < 77; ++k) s += __expf(ls[k]-m);
  if (t < 77) ps[t] = __expf(ls[t]-m) / s;
  __syncthreads();
  if (t < 4){
    float acc = 0.f;
    const float* tp = tip + (size_t)b*77*4 + t;
    for (int k = 0; k < 77; ++k) acc += ps[k]*tp[k*4];
    sem[(size_t)row*4 + t] = acc;
  }
}

// ---------------- fused text+ip attention ----------------
__global__ __launch_bounds__(256) void attn_k(
    const ushort* __restrict__ qb, const ushort* __restrict__ pall,
    const float* __restrict__ sem, const float* __restrict__ mask,
    ushort* __restrict__ hmid)
{
  int qt = blockIdx.x;   // 0..15
  int h  = blockIdx.y;   // 0..19
  int b  = blockIdx.z;   // 0..3
  __shared__ float kh[77][64];
  __shared__ float vh[77][64];
  __shared__ float ipk[4][64];
  __shared__ float ipv[4][64];
  int t = threadIdx.x;
  const ushort* base = pall + (size_t)(b*81)*5120 + h*64;
  for (int idx = t; idx < 77*64; idx += 256){
    int k = idx >> 6, d = idx & 63;
    kh[k][d] = b2f(base[(size_t)k*5120 + d]);
    vh[k][d] = b2f(base[(size_t)k*5120 + 1280 + d]);
  }
  {
    int n = t >> 6, d = t & 63;
    ipk[n][d] = b2f(base[(size_t)(77+n)*5120 + 2560 + d]);
    ipv[n][d] = b2f(base[(size_t)(77+n)*5120 + 3840 + d]);
  }
  int srow = qt*256 + t;
  size_t qrow = (size_t)b*4096 + srow;
  f32x4 qv[16];
  {
    const uint4* qp = reinterpret_cast<const uint4*>(qb + qrow*1280 + h*64);
    #pragma unroll
    for (int i = 0; i < 8; ++i){
      uint4 u = qp[i];
      f32x4 a, c;
      a.x = b2f((ushort)(u.x & 0xffff)); a.y = b2f((ushort)(u.x >> 16));
      a.z = b2f((ushort)(u.y & 0xffff)); a.w = b2f((ushort)(u.y >> 16));
      c.x = b2f((ushort)(u.z & 0xffff)); c.y = b2f((ushort)(u.z >> 16));
      c.z = b2f((ushort)(u.w & 0xffff)); c.w = b2f((ushort)(u.w >> 16));
      qv[2*i] = a; qv[2*i+1] = c;
    }
  }
  __syncthreads();

  // pass 1: online max + sumexp over 77 text keys
  float m = -1e30f, ssum = 0.f;
  for (int k = 0; k < 77; ++k){
    const f32x4* kr = reinterpret_cast<const f32x4*>(kh[k]);
    float d0 = 0.f;
    #pragma unroll
    for (int i = 0; i < 16; ++i){
      f32x4 kv = kr[i];
      d0 += qv[i].x*kv.x + qv[i].y*kv.y + qv[i].z*kv.z + qv[i].w*kv.w;
    }
    float lg = d0 * 0.125f;
    float mn = fmaxf(m, lg);
    ssum = ssum * __expf(m - mn) + __expf(lg - mn);
    m = mn;
  }
  float inv = 1.f / ssum;

  // pass 2: recompute logits, accumulate p*v
  f32x4 av[16];
  #pragma unroll
  for (int i = 0; i < 16; ++i) av[i] = (f32x4){0.f,0.f,0.f,0.f};
  for (int k = 0; k < 77; ++k){
    const f32x4* kr = reinterpret_cast<const f32x4*>(kh[k]);
    float d0 = 0.f;
    #pragma unroll
    for (int i = 0; i < 16; ++i){
      f32x4 kv = kr[i];
      d0 += qv[i].x*kv.x + qv[i].y*kv.y + qv[i].z*kv.z + qv[i].w*kv.w;
    }
    float p = __expf(d0*0.125f - m) * inv;
    const f32x4* vr = reinterpret_cast<const f32x4*>(vh[k]);
    #pragma unroll
    for (int i = 0; i < 16; ++i) av[i] += p * vr[i];
  }

  // ip attention: 4 keys, + 0.5*sem, softmax, * mask
  float fl[4];
  const float* sp = sem + qrow*4;
  #pragma unroll
  for (int n = 0; n < 4; ++n){
    const f32x4* kr = reinterpret_cast<const f32x4*>(ipk[n]);
    float d0 = 0.f;
    #pragma unroll
    for (int i = 0; i < 16; ++i){
      f32x4 kv = kr[i];
      d0 += qv[i].x*kv.x + qv[i].y*kv.y + qv[i].z*kv.z + qv[i].w*kv.w;
    }
    fl[n] = d0*0.125f + 0.5f*sp[n];
  }
  float m2 = fmaxf(fmaxf(fl[0],fl[1]), fmaxf(fl[2],fl[3]));
  float e[4]; float s2 = 0.f;
  #pragma unroll
  for (int n = 0; n < 4; ++n){ e[n] = __expf(fl[n]-m2); s2 += e[n]; }
  float sc = mask[srow] / s2;
  #pragma unroll
  for (int n = 0; n < 4; ++n){
    float pn = e[n]*sc;
    const f32x4* vr = reinterpret_cast<const f32x4*>(ipv[n]);
    #pragma unroll
    for (int i = 0; i < 16; ++i) av[i] += pn * vr[i];
  }

  ushort* op = hmid + qrow*1280 + h*64;
  #pragma unroll
  for (int i = 0; i < 16; ++i){
    ushort4 o = make_ushort4(f2b(av[i].x), f2b(av[i].y), f2b(av[i].z), f2b(av[i].w));
    reinterpret_cast<ushort4*>(op)[i] = o;
  }
}

extern "C" void kernel_launch(void* const* d_in, const int* in_sizes, int n_in,
                              void* d_out, int out_size, void* d_ws, size_t ws_size,
                              hipStream_t stream)
{
  (void)in_sizes; (void)n_in; (void)out_size; (void)ws_size;
  const float* hs   = (const float*)d_in[0];
  const float* enc  = (const float*)d_in[1];
  const float* mask = (const float*)d_in[2];
  const float* Wq   = (const float*)d_in[3];
  const float* Wk   = (const float*)d_in[4];
  const float* Wv   = (const float*)d_in[5];
  const float* Wkip = (const float*)d_in[6];
  const float* Wvip = (const float*)d_in[7];
  const float* Wout = (const float*)d_in[8];
  const float* bout = (const float*)d_in[9];
  float* out = (float*)d_out;
  char* ws = (char*)d_ws;

  size_t off = 0;
  auto alloc = [&](size_t bytes)->char*{
    char* p = ws + off; off += (bytes + 255) & ~(size_t)255; return p;
  };
  ushort* hs_bf   = (ushort*)alloc(16384ull*1280*2);   // also reused as hmid
  ushort* q_bf    = (ushort*)alloc(16384ull*1280*2);
  ushort* enc_bf  = (ushort*)alloc(384ull*2048*2);
  ushort* wqt     = (ushort*)alloc(1280ull*1280*2);
  ushort* woutt   = (ushort*)alloc(1280ull*1280*2);
  ushort* wcat    = (ushort*)alloc(5120ull*2048*2);
  ushort* pall    = (ushort*)alloc(384ull*5120*2);
  float*  logits  = (float*)alloc(16384ull*128*4);
  float*  tip     = (float*)alloc(4ull*77*4*4);
  float*  semb    = (float*)alloc(16384ull*4*4);
  ushort* hmid_bf = hs_bf; // alias: hs_bf consumed before attn writes hmid

  // converts + weight transposes
  cvt_bf16_k<<<20480, 256, 0, stream>>>(hs, hs_bf, 16384*1280/4);
  cvt_enc_k<<<768, 256, 0, stream>>>(enc, enc_bf);
  transpose_bf16_k<<<dim3(40,40), 256, 0, stream>>>(Wq,   wqt,   1280, 1280);
  transpose_bf16_k<<<dim3(40,40), 256, 0, stream>>>(Wout, woutt, 1280, 1280);
  transpose_bf16_k<<<dim3(40,64), 256, 0, stream>>>(Wk,   wcat + 0ull*1280*2048, 2048, 1280);
  transpose_bf16_k<<<dim3(40,64), 256, 0, stream>>>(Wv,   wcat + 1ull*1280*2048, 2048, 1280);
  transpose_bf16_k<<<dim3(40,64), 256, 0, stream>>>(Wkip, wcat + 2ull*1280*2048, 2048, 1280);
  transpose_bf16_k<<<dim3(40,64), 256, 0, stream>>>(Wvip, wcat + 3ull*1280*2048, 2048, 1280);

  // encoder projections: pall[384][5120] = enc_bf @ wcat^T  (bf16 out)
  gemm64<<<dim3((384/64)*(5120/64),1,1), 256, 0, stream>>>(enc_bf, wcat, 384, 5120, 2048,
      2048, 2048, 5120, 0, 0, 0, nullptr, pall, nullptr, nullptr, 0);

  // q = hs @ Wq (bf16 out)
  gemm64<<<dim3((16384/64)*(1280/64),1,1), 256, 0, stream>>>(hs_bf, wqt, 16384, 1280, 1280,
      1280, 1280, 1280, 0, 0, 0, nullptr, q_bf, nullptr, nullptr, 0);

  // T_ip
  tip_k<<<dim3(77,4,4), 64, 0, stream>>>(enc, tip);

  // logits[b][4096][128] = q @ k_text^T  (batched over b; N padded to 128)
  gemm64<<<dim3((4096/64)*(128/64),1,4), 256, 0, stream>>>(q_bf, pall, 4096, 128, 1280,
      1280, 5120, 128, 4096ll*1280, 81ll*5120, 4096ll*128, logits, nullptr, nullptr, nullptr, 2);

  // softmax + sem
  semsm_k<<<16384, 128, 0, stream>>>(logits, tip, semb);

  // fused attention -> hmid (bf16)
  attn_k<<<dim3(16,20,4), 256, 0, stream>>>(q_bf, pall, semb, mask, hmid_bf);

  // out = hmid @ Wout + bout + residual
  gemm64<<<dim3((16384/64)*(1280/64),1,1), 256, 0, stream>>>(hmid_bf, woutt, 16384, 1280, 1280,
      1280, 1280, 1280, 0, 0, 0, out, nullptr, bout, hs, 1);
}

// Round 2
// 440.612 us; speedup vs baseline: 1.5465x; 1.5465x over previous
//
#include <hip/hip_runtime.h>

typedef __bf16 bf16x8 __attribute__((ext_vector_type(8)));
typedef float f32x4 __attribute__((ext_vector_type(4)));

__device__ __forceinline__ ushort f2b(float f){
  union { float f; unsigned u; } v; v.f = f;
  unsigned r = v.u + 0x7FFFu + ((v.u >> 16) & 1u);
  return (ushort)(r >> 16);
}
__device__ __forceinline__ float b2f(ushort b){
  union { unsigned u; float f; } v; v.u = ((unsigned)b) << 16; return v.f;
}

__device__ __forceinline__ void gload16(const ushort* g, ushort* lds){
  __builtin_amdgcn_global_load_lds(
      (const __attribute__((address_space(1))) unsigned int*)(g),
      (__attribute__((address_space(3))) unsigned int*)(lds), 16, 0, 0);
}

// ---------------- converts ----------------
__global__ __launch_bounds__(256) void cvt_bf16_k(const float* __restrict__ in,
                                                  ushort* __restrict__ out, int n4){
  int i = blockIdx.x*256 + threadIdx.x;
  if (i < n4){
    f32x4 v = reinterpret_cast<const f32x4*>(in)[i];
    ushort4 o = make_ushort4(f2b(v.x), f2b(v.y), f2b(v.z), f2b(v.w));
    reinterpret_cast<ushort4*>(out)[i] = o;
  }
}

__global__ __launch_bounds__(256) void cvt_enc_k(const float* __restrict__ in,
                                                 ushort* __restrict__ out){
  int i = blockIdx.x*256 + threadIdx.x;
  if (i < 384*2048/4){
    f32x4 v = {0.f,0.f,0.f,0.f};
    if (i < 324*2048/4) v = reinterpret_cast<const f32x4*>(in)[i];
    ushort4 o = make_ushort4(f2b(v.x), f2b(v.y), f2b(v.z), f2b(v.w));
    reinterpret_cast<ushort4*>(out)[i] = o;
  }
}

// W[K][N] fp32 -> Wt[N][K] bf16
__global__ __launch_bounds__(256) void transpose_bf16_k(const float* __restrict__ W,
                                                        ushort* __restrict__ Wt, int K, int N){
  __shared__ float tile[32][33];
  int n0 = blockIdx.x*32, k0 = blockIdx.y*32;
  int tx = threadIdx.x & 31, ty = threadIdx.x >> 5;
  for (int i = ty; i < 32; i += 8) tile[i][tx] = W[(size_t)(k0+i)*N + n0+tx];
  __syncthreads();
  for (int i = ty; i < 32; i += 8) Wt[(size_t)(n0+i)*K + k0+tx] = f2b(tile[tx][i]);
}

// ---------------- 128x128 GEMM (m97 structure): C = A[M][K] @ Bt[N][K]^T ----------------
// MODE 0: bf16 store; MODE 1: fp32 + bias[col] + resid
template<int MODE>
__global__ __launch_bounds__(256) void gemm128(
    const ushort* __restrict__ A, const ushort* __restrict__ Bt,
    int M, int N, int K, int lda, int ldb, int ldo,
    float* __restrict__ outF, ushort* __restrict__ outB,
    const float* __restrict__ bias, const float* __restrict__ resid)
{
  __shared__ ushort As[128][32];
  __shared__ ushort Bs[128][32];
  int ntiles = N >> 7;
  int mt = blockIdx.x / ntiles;
  int nt = blockIdx.x - mt*ntiles;
  int t = threadIdx.x;
  int w = t >> 6, l = t & 63;
  int wr = w >> 1, wc = w & 1;
  int fr = l & 15, fq = l >> 4, fkb = (l >> 4) << 3;

  const ushort* Ag = A + (size_t)(mt*128 + (t>>2))*lda + ((t&3)<<3);
  const ushort* Bg = Bt + (size_t)(nt*128 + (t>>2))*ldb + ((t&3)<<3);
  ushort* Al = &As[0][0] + t*8;
  ushort* Bl = &Bs[0][0] + t*8;

  f32x4 acc[4][4];
  #pragma unroll
  for (int m = 0; m < 4; ++m)
    #pragma unroll
    for (int n = 0; n < 4; ++n) acc[m][n] = (f32x4){0.f,0.f,0.f,0.f};

  for (int k0 = 0; k0 < K; k0 += 32){
    if (k0) __syncthreads();
    gload16(Ag + k0, Al);
    gload16(Ag + 64*lda + k0, Al + 2048);
    gload16(Bg + k0, Bl);
    gload16(Bg + 64*ldb + k0, Bl + 2048);
    __syncthreads();
    bf16x8 af[4], bf[4];
    #pragma unroll
    for (int m = 0; m < 4; ++m) af[m] = *reinterpret_cast<const bf16x8*>(&As[wr*64 + m*16 + fr][fkb]);
    #pragma unroll
    for (int n = 0; n < 4; ++n) bf[n] = *reinterpret_cast<const bf16x8*>(&Bs[wc*64 + n*16 + fr][fkb]);
    #pragma unroll
    for (int m = 0; m < 4; ++m)
      #pragma unroll
      for (int n = 0; n < 4; ++n)
        acc[m][n] = __builtin_amdgcn_mfma_f32_16x16x32_bf16(af[m], bf[n], acc[m][n], 0, 0, 0);
  }

  #pragma unroll
  for (int m = 0; m < 4; ++m){
    #pragma unroll
    for (int n = 0; n < 4; ++n){
      #pragma unroll
      for (int r = 0; r < 4; ++r){
        int row = mt*128 + wr*64 + m*16 + fq*4 + r;
        int col = nt*128 + wc*64 + n*16 + fr;
        size_t oidx = (size_t)row*ldo + col;
        float v = acc[m][n][r];
        if (MODE == 0) outB[oidx] = f2b(v);
        else           outF[oidx] = v + bias[col] + resid[oidx];
      }
    }
  }
}

// ---------------- 64x64 GEMM (batched, for logits) ----------------
__global__ __launch_bounds__(256) void gemm64(
    const ushort* __restrict__ A, const ushort* __restrict__ Bt,
    int M, int N, int K, int lda, int ldb, int ldo,
    long long sA, long long sB, long long sO, float* __restrict__ outF)
{
  __shared__ ushort As[64][40];
  __shared__ ushort Bs[64][40];
  int ntiles = N >> 6;
  int mt = blockIdx.x / ntiles;
  int nt = blockIdx.x - mt*ntiles;
  int z  = blockIdx.z;
  const ushort* Ab = A + (size_t)z*sA;
  const ushort* Bb = Bt + (size_t)z*sB;
  int t = threadIdx.x;
  int w = t >> 6, l = t & 63;
  int lr = t >> 2, lc = (t & 3) << 3;
  int fr = l & 15, fk = (l >> 4) << 3;
  f32x4 acc[4];
  #pragma unroll
  for (int n = 0; n < 4; ++n) acc[n] = (f32x4){0.f,0.f,0.f,0.f};

  const ushort* Aptr = Ab + (size_t)(mt*64 + lr)*lda + lc;
  const ushort* Bptr = Bb + (size_t)(nt*64 + lr)*ldb + lc;
  for (int k0 = 0; k0 < K; k0 += 32){
    uint4 av = *reinterpret_cast<const uint4*>(Aptr + k0);
    uint4 bv = *reinterpret_cast<const uint4*>(Bptr + k0);
    __syncthreads();
    *reinterpret_cast<uint4*>(&As[lr][lc]) = av;
    *reinterpret_cast<uint4*>(&Bs[lr][lc]) = bv;
    __syncthreads();
    bf16x8 af = *reinterpret_cast<const bf16x8*>(&As[w*16 + fr][fk]);
    #pragma unroll
    for (int n = 0; n < 4; ++n){
      bf16x8 bf = *reinterpret_cast<const bf16x8*>(&Bs[n*16 + fr][fk]);
      acc[n] = __builtin_amdgcn_mfma_f32_16x16x32_bf16(af, bf, acc[n], 0, 0, 0);
    }
  }
  int fq = l >> 4;
  #pragma unroll
  for (int n = 0; n < 4; ++n){
    #pragma unroll
    for (int r = 0; r < 4; ++r){
      int row = mt*64 + w*16 + fq*4 + r;
      int col = nt*64 + n*16 + fr;
      outF[(size_t)z*sO + (size_t)row*ldo + col] = acc[n][r];
    }
  }
}

// ---------------- T_ip[b][k][n] = 0.125 * sum_c text[b,k,c]*ip[b,n,c] ----------------
__global__ __launch_bounds__(64) void tip_k(const float* __restrict__ enc, float* __restrict__ tip){
  int k = blockIdx.x, n = blockIdx.y, b = blockIdx.z;
  const float* text = enc + ((size_t)b*81 + k)*2048;
  const float* ip   = enc + ((size_t)b*81 + 77 + n)*2048;
  int l = threadIdx.x;
  float acc = 0.f;
  for (int c = l; c < 2048; c += 64) acc += text[c]*ip[c];
  for (int off = 32; off > 0; off >>= 1) acc += __shfl_down(acc, off);
  if (l == 0) tip[((size_t)b*77 + k)*4 + n] = acc * 0.125f;
}

// ---------------- softmax over 77 logits + sem = p @ T_ip ----------------
__global__ __launch_bounds__(128) void semsm_k(const float* __restrict__ logits,
    const float* __restrict__ tip, float* __restrict__ sem)
{
  int row = blockIdx.x;
  int b = row >> 12;
  int t = threadIdx.x;
  __shared__ float ls[77];
  __shared__ float ps[77];
  if (t < 77) ls[t] = logits[(size_t)row*128 + t] * 0.125f;
  __syncthreads();
  float m = -1e30f;
  for (int k = 0; k < 77; ++k) m = fmaxf(m, ls[k]);
  float s = 0.f;
  for (int k = 0; k < 77; ++k) s += __expf(ls[k]-m);
  if (t < 77) ps[t] = __expf(ls[t]-m) / s;
  __syncthreads();
  if (t < 4){
    float acc = 0.f;
    const float* tp = tip + (size_t)b*77*4 + t;
    for (int k = 0; k < 77; ++k) acc += ps[k]*tp[k*4];
    sem[(size_t)row*4 + t] = acc;
  }
}

// ---------------- MFMA fused text+ip attention ----------------
// block: 64 q-rows x head h x batch b.  S = Q[64x64] @ K[96x64]^T, dual softmax, P@V.
__global__ __launch_bounds__(256) void attn_mfma_k(
    const ushort* __restrict__ qb, const ushort* __restrict__ pall,
    const float* __restrict__ sem, const float* __restrict__ mask,
    ushort* __restrict__ hmid)
{
  int qt = blockIdx.x;   // 0..63
  int h  = blockIdx.y;   // 0..19
  int b  = blockIdx.z;   // 0..3
  __shared__ ushort Qs[64][72];
  __shared__ ushort Ks[96][72];
  __shared__ ushort Vt[64][104];  // V^T: [d][k]
  __shared__ ushort Ps[64][104];
  int t = threadIdx.x;
  int w = t >> 6, l = t & 63;
  const ushort* pb = pall + (size_t)b*81*5120 + h*64;

  // stage Q (64x64, uint4 chunks)
  {
    int base = b*4096 + qt*64;
    #pragma unroll
    for (int it = 0; it < 2; ++it){
      int chunk = t + it*256;
      int r = chunk >> 3, dp = (chunk & 7) << 3;
      uint4 v = *reinterpret_cast<const uint4*>(qb + (size_t)(base + r)*1280 + h*64 + dp);
      *reinterpret_cast<uint4*>(&Qs[r][dp]) = v;
    }
  }
  // stage K rows 0..76 text, 77..80 ip, 81..95 zero (ushort4 chunks)
  #pragma unroll
  for (int it = 0; it < 6; ++it){
    int chunk = t + it*256;
    int k = chunk >> 4, dp = (chunk & 15) << 2;
    ushort4 v = make_ushort4(0,0,0,0);
    if (k < 77)      v = *reinterpret_cast<const ushort4*>(pb + (size_t)k*5120 + dp);
    else if (k < 81) v = *reinterpret_cast<const ushort4*>(pb + (size_t)k*5120 + 2560 + dp);
    *reinterpret_cast<ushort4*>(&Ks[k][dp]) = v;
  }
  // stage V transposed
  #pragma unroll
  for (int it = 0; it < 24; ++it){
    int idx = t + it*256;
    int k = idx >> 6, d = idx & 63;
    ushort v = 0;
    if (k < 77)      v = pb[(size_t)k*5120 + 1280 + d];
    else if (k < 81) v = pb[(size_t)k*5120 + 3840 + d];
    Vt[d][k] = v;
  }
  __syncthreads();

  int fr = l & 15, fq = l >> 4, fkb = fq << 3;
  int c = fr;

  // S = Q @ K^T   (wave w: rows w*16..+15, all 96 cols)
  f32x4 s[6];
  #pragma unroll
  for (int n = 0; n < 6; ++n) s[n] = (f32x4){0.f,0.f,0.f,0.f};
  #pragma unroll
  for (int ks = 0; ks < 2; ++ks){
    bf16x8 aq = *reinterpret_cast<const bf16x8*>(&Qs[w*16 + fr][ks*32 + fkb]);
    #pragma unroll
    for (int n = 0; n < 6; ++n){
      bf16x8 bk = *reinterpret_cast<const bf16x8*>(&Ks[n*16 + fr][ks*32 + fkb]);
      s[n] = __builtin_amdgcn_mfma_f32_16x16x32_bf16(aq, bk, s[n], 0, 0, 0);
    }
  }

  int rowbase = qt*64 + w*16 + (fq << 2);
  #pragma unroll
  for (int r = 0; r < 4; ++r){
    float lg[6];
    #pragma unroll
    for (int n = 0; n < 6; ++n) lg[n] = s[n][r]*0.125f;

    // text softmax: cols < 77 (frags 0..3 full; frag4 c<13)
    float mt = fmaxf(fmaxf(lg[0],lg[1]), fmaxf(lg[2],lg[3]));
    if (c < 13) mt = fmaxf(mt, lg[4]);
    #pragma unroll
    for (int off = 1; off < 16; off <<= 1) mt = fmaxf(mt, __shfl_xor(mt, off));
    float st = __expf(lg[0]-mt) + __expf(lg[1]-mt) + __expf(lg[2]-mt) + __expf(lg[3]-mt);
    if (c < 13) st += __expf(lg[4]-mt);
    #pragma unroll
    for (int off = 1; off < 16; off <<= 1) st += __shfl_xor(st, off);
    float invst = 1.f/st;

    // ip softmax: cols 77..80 = frag4 c>=13 (j=c-13), frag5 c==0 (j=3)
    size_t qrow = (size_t)b*4096 + rowbase + r;
    float f4 = -1e30f, f5 = -1e30f;
    if (c >= 13) f4 = lg[4] + 0.5f*sem[qrow*4 + (c-13)];
    if (c == 0)  f5 = lg[5] + 0.5f*sem[qrow*4 + 3];
    float m2 = fmaxf(f4, f5);
    #pragma unroll
    for (int off = 1; off < 16; off <<= 1) m2 = fmaxf(m2, __shfl_xor(m2, off));
    float si = (c >= 13 ? __expf(f4-m2) : 0.f) + (c == 0 ? __expf(f5-m2) : 0.f);
    #pragma unroll
    for (int off = 1; off < 16; off <<= 1) si += __shfl_xor(si, off);
    float pmul = mask[rowbase + r] / si;

    int prow = w*16 + (fq << 2) + r;
    #pragma unroll
    for (int n = 0; n < 4; ++n) Ps[prow][n*16 + c] = f2b(__expf(lg[n]-mt)*invst);
    Ps[prow][64 + c] = f2b(c < 13 ? __expf(lg[4]-mt)*invst : __expf(f4-m2)*pmul);
    Ps[prow][80 + c] = f2b(c == 0 ? __expf(f5-m2)*pmul : 0.f);
  }
  __syncthreads();

  // out = P @ V   (K=96)
  f32x4 o[4];
  #pragma unroll
  for (int df = 0; df < 4; ++df) o[df] = (f32x4){0.f,0.f,0.f,0.f};
  #pragma unroll
  for (int ks = 0; ks < 3; ++ks){
    bf16x8 ap = *reinterpret_cast<const bf16x8*>(&Ps[w*16 + fr][ks*32 + fkb]);
    #pragma unroll
    for (int df = 0; df < 4; ++df){
      bf16x8 bv = *reinterpret_cast<const bf16x8*>(&Vt[df*16 + fr][ks*32 + fkb]);
      o[df] = __builtin_amdgcn_mfma_f32_16x16x32_bf16(ap, bv, o[df], 0, 0, 0);
    }
  }
  #pragma unroll
  for (int df = 0; df < 4; ++df)
    #pragma unroll
    for (int r = 0; r < 4; ++r)
      hmid[((size_t)b*4096 + rowbase + r)*1280 + h*64 + df*16 + c] = f2b(o[df][r]);
}

extern "C" void kernel_launch(void* const* d_in, const int* in_sizes, int n_in,
                              void* d_out, int out_size, void* d_ws, size_t ws_size,
                              hipStream_t stream)
{
  (void)in_sizes; (void)n_in; (void)out_size; (void)ws_size;
  const float* hs   = (const float*)d_in[0];
  const float* enc  = (const float*)d_in[1];
  const float* mask = (const float*)d_in[2];
  const float* Wq   = (const float*)d_in[3];
  const float* Wk   = (const float*)d_in[4];
  const float* Wv   = (const float*)d_in[5];
  const float* Wkip = (const float*)d_in[6];
  const float* Wvip = (const float*)d_in[7];
  const float* Wout = (const float*)d_in[8];
  const float* bout = (const float*)d_in[9];
  float* out = (float*)d_out;
  char* ws = (char*)d_ws;

  size_t off = 0;
  auto alloc = [&](size_t bytes)->char*{
    char* p = ws + off; off += (bytes + 255) & ~(size_t)255; return p;
  };
  ushort* hs_bf   = (ushort*)alloc(16384ull*1280*2);   // reused as hmid
  ushort* q_bf    = (ushort*)alloc(16384ull*1280*2);
  ushort* enc_bf  = (ushort*)alloc(384ull*2048*2);
  ushort* wqt     = (ushort*)alloc(1280ull*1280*2);
  ushort* woutt   = (ushort*)alloc(1280ull*1280*2);
  ushort* wcat    = (ushort*)alloc(5120ull*2048*2);
  ushort* pall    = (ushort*)alloc(384ull*5120*2);
  float*  logits  = (float*)alloc(16384ull*128*4);
  float*  tip     = (float*)alloc(4ull*77*4*4);
  float*  semb    = (float*)alloc(16384ull*4*4);
  ushort* hmid_bf = hs_bf;

  cvt_bf16_k<<<20480, 256, 0, stream>>>(hs, hs_bf, 16384*1280/4);
  cvt_enc_k<<<768, 256, 0, stream>>>(enc, enc_bf);
  transpose_bf16_k<<<dim3(40,40), 256, 0, stream>>>(Wq,   wqt,   1280, 1280);
  transpose_bf16_k<<<dim3(40,40), 256, 0, stream>>>(Wout, woutt, 1280, 1280);
  transpose_bf16_k<<<dim3(40,64), 256, 0, stream>>>(Wk,   wcat + 0ull*1280*2048, 2048, 1280);
  transpose_bf16_k<<<dim3(40,64), 256, 0, stream>>>(Wv,   wcat + 1ull*1280*2048, 2048, 1280);
  transpose_bf16_k<<<dim3(40,64), 256, 0, stream>>>(Wkip, wcat + 2ull*1280*2048, 2048, 1280);
  transpose_bf16_k<<<dim3(40,64), 256, 0, stream>>>(Wvip, wcat + 3ull*1280*2048, 2048, 1280);

  // encoder projections: pall[384][5120] = enc_bf @ wcat^T  (bf16 out)
  gemm128<0><<<dim3((384/128)*(5120/128)), 256, 0, stream>>>(enc_bf, wcat, 384, 5120, 2048,
      2048, 2048, 5120, nullptr, pall, nullptr, nullptr);

  // q = hs @ Wq (bf16 out)
  gemm128<0><<<dim3((16384/128)*(1280/128)), 256, 0, stream>>>(hs_bf, wqt, 16384, 1280, 1280,
      1280, 1280, 1280, nullptr, q_bf, nullptr, nullptr);

  tip_k<<<dim3(77,4,4), 64, 0, stream>>>(enc, tip);

  // logits[b][4096][128] = q @ k_text^T  (batched; N padded to 128)
  gemm64<<<dim3((4096/64)*(128/64),1,4), 256, 0, stream>>>(q_bf, pall, 4096, 128, 1280,
      1280, 5120, 128, 4096ll*1280, 81ll*5120, 4096ll*128, logits);

  semsm_k<<<16384, 128, 0, stream>>>(logits, tip, semb);

  attn_mfma_k<<<dim3(64,20,4), 256, 0, stream>>>(q_bf, pall, semb, mask, hmid_bf);

  // out = hmid @ Wout + bout + residual
  gemm128<1><<<dim3((16384/128)*(1280/128)), 256, 0, stream>>>(hmid_bf, woutt, 16384, 1280, 1280,
      1280, 1280, 1280, out, nullptr, bout, hs);
}

// Round 3
// 389.395 us; speedup vs baseline: 1.7499x; 1.1315x over previous
//
#include <hip/hip_runtime.h>

typedef __bf16 bf16x8 __attribute__((ext_vector_type(8)));
typedef float f32x4 __attribute__((ext_vector_type(4)));

__device__ __forceinline__ ushort f2b(float f){
  union { float f; unsigned u; } v; v.f = f;
  unsigned r = v.u + 0x7FFFu + ((v.u >> 16) & 1u);
  return (ushort)(r >> 16);
}
__device__ __forceinline__ float b2f(ushort b){
  union { unsigned u; float f; } v; v.u = ((unsigned)b) << 16; return v.f;
}

__device__ __forceinline__ void gload16(const ushort* g, ushort* lds){
  __builtin_amdgcn_global_load_lds(
      (const __attribute__((address_space(1))) unsigned int*)(g),
      (__attribute__((address_space(3))) unsigned int*)(lds), 16, 0, 0);
}

// ---------------- converts ----------------
__global__ __launch_bounds__(256) void cvt_bf16_k(const float* __restrict__ in,
                                                  ushort* __restrict__ out, int n4){
  int i = blockIdx.x*256 + threadIdx.x;
  if (i < n4){
    f32x4 v = reinterpret_cast<const f32x4*>(in)[i];
    ushort4 o = make_ushort4(f2b(v.x), f2b(v.y), f2b(v.z), f2b(v.w));
    reinterpret_cast<ushort4*>(out)[i] = o;
  }
}

__global__ __launch_bounds__(256) void cvt_enc_k(const float* __restrict__ in,
                                                 ushort* __restrict__ out){
  int i = blockIdx.x*256 + threadIdx.x;
  if (i < 384*2048/4){
    f32x4 v = {0.f,0.f,0.f,0.f};
    if (i < 324*2048/4) v = reinterpret_cast<const f32x4*>(in)[i];
    ushort4 o = make_ushort4(f2b(v.x), f2b(v.y), f2b(v.z), f2b(v.w));
    reinterpret_cast<ushort4*>(out)[i] = o;
  }
}

// W[K][N] fp32 -> Wt[N][K] bf16
__global__ __launch_bounds__(256) void transpose_bf16_k(const float* __restrict__ W,
                                                        ushort* __restrict__ Wt, int K, int N){
  __shared__ float tile[32][33];
  int n0 = blockIdx.x*32, k0 = blockIdx.y*32;
  int tx = threadIdx.x & 31, ty = threadIdx.x >> 5;
  for (int i = ty; i < 32; i += 8) tile[i][tx] = W[(size_t)(k0+i)*N + n0+tx];
  __syncthreads();
  for (int i = ty; i < 32; i += 8) Wt[(size_t)(n0+i)*K + k0+tx] = f2b(tile[tx][i]);
}

// ---------------- 128x128 GEMM, BK=64, double-buffered 2-phase, swizzled LDS ----------------
// MODE 0: bf16 store; MODE 1: fp32 + bias[col] + resid
// LDS tile [128 rows][64 cols] bf16, row = 128B. XOR swizzle: byte ^= (row&7)<<4,
// applied on the GLOBAL source address (gload_lds dest linear) and on ds_read.
template<int MODE>
__global__ __launch_bounds__(256) void gemm128(
    const ushort* __restrict__ A, const ushort* __restrict__ Bt,
    int M, int N, int K, int lda, int ldb, int ldo,
    float* __restrict__ outF, ushort* __restrict__ outB,
    const float* __restrict__ bias, const float* __restrict__ resid)
{
  __shared__ ushort As[2][128*64];
  __shared__ ushort Bs[2][128*64];
  int ntiles = N >> 7;
  int nwg = gridDim.x;
  int bid = blockIdx.x;
  // bijective XCD swizzle (all grids here are %8==0; guard anyway)
  if ((nwg & 7) == 0){
    int cpx = nwg >> 3;
    bid = (bid & 7)*cpx + (bid >> 3);
  }
  int mt = bid / ntiles;
  int nt = bid - mt*ntiles;
  int t = threadIdx.x;
  int w = t >> 6, l = t & 63;
  int wr = w >> 1, wc = w & 1;
  int fr = l & 15, fq = l >> 4;

  const char* Agb = (const char*)(A + (size_t)(mt*128)*lda);
  const char* Bgb = (const char*)(Bt + (size_t)(nt*128)*ldb);
  // per-thread staging geometry: chunk c = t + j*256; row=c>>3, byte=(c&7)*16
  int srow = t >> 3;
  int sbyte = (t & 7) << 4;

  f32x4 acc[4][4];
  #pragma unroll
  for (int m = 0; m < 4; ++m)
    #pragma unroll
    for (int n = 0; n < 4; ++n) acc[m][n] = (f32x4){0.f,0.f,0.f,0.f};

  auto stage = [&](int buf, int kt){
    size_t kb = (size_t)(kt*64)*2;   // byte offset of K-tile start within row
    #pragma unroll
    for (int j = 0; j < 4; ++j){
      int r = srow + j*32;
      int bs = sbyte ^ ((r & 7) << 4);
      gload16((const ushort*)(Agb + (size_t)r*(lda*2) + kb + bs), &As[buf][0] + (t + j*256)*8);
      gload16((const ushort*)(Bgb + (size_t)r*(ldb*2) + kb + bs), &Bs[buf][0] + (t + j*256)*8);
    }
  };
  auto frag = [&](const ushort* lbuf, int row, int cb)->bf16x8{
    int b = cb ^ ((row & 7) << 4);
    return *reinterpret_cast<const bf16x8*>((const char*)lbuf + row*128 + b);
  };
  auto compute = [&](int buf){
    bf16x8 af[2][4], bf[2][4];
    #pragma unroll
    for (int kk = 0; kk < 2; ++kk){
      #pragma unroll
      for (int m = 0; m < 4; ++m) af[kk][m] = frag(&As[buf][0], wr*64 + m*16 + fr, kk*64 + fq*16);
      #pragma unroll
      for (int n = 0; n < 4; ++n) bf[kk][n] = frag(&Bs[buf][0], wc*64 + n*16 + fr, kk*64 + fq*16);
    }
    #pragma unroll
    for (int kk = 0; kk < 2; ++kk)
      #pragma unroll
      for (int m = 0; m < 4; ++m)
        #pragma unroll
        for (int n = 0; n < 4; ++n)
          acc[m][n] = __builtin_amdgcn_mfma_f32_16x16x32_bf16(af[kk][m], bf[kk][n], acc[m][n], 0, 0, 0);
  };

  int nk = K >> 6;
  stage(0, 0);
  __syncthreads();
  int cur = 0;
  for (int kt = 0; kt < nk - 1; ++kt){
    stage(cur ^ 1, kt + 1);
    compute(cur);
    __syncthreads();
    cur ^= 1;
  }
  compute(cur);

  int fqb = fq << 2;
  #pragma unroll
  for (int m = 0; m < 4; ++m){
    #pragma unroll
    for (int n = 0; n < 4; ++n){
      #pragma unroll
      for (int r = 0; r < 4; ++r){
        int row = mt*128 + wr*64 + m*16 + fqb + r;
        int col = nt*128 + wc*64 + n*16 + fr;
        size_t oidx = (size_t)row*ldo + col;
        float v = acc[m][n][r];
        if (MODE == 0) outB[oidx] = f2b(v);
        else           outF[oidx] = v + bias[col] + resid[oidx];
      }
    }
  }
}

// ---------------- 64x64 GEMM (batched, for logits) ----------------
__global__ __launch_bounds__(256) void gemm64(
    const ushort* __restrict__ A, const ushort* __restrict__ Bt,
    int M, int N, int K, int lda, int ldb, int ldo,
    long long sA, long long sB, long long sO, float* __restrict__ outF)
{
  __shared__ ushort As[64][40];
  __shared__ ushort Bs[64][40];
  int ntiles = N >> 6;
  int mt = blockIdx.x / ntiles;
  int nt = blockIdx.x - mt*ntiles;
  int z  = blockIdx.z;
  const ushort* Ab = A + (size_t)z*sA;
  const ushort* Bb = Bt + (size_t)z*sB;
  int t = threadIdx.x;
  int w = t >> 6, l = t & 63;
  int lr = t >> 2, lc = (t & 3) << 3;
  int fr = l & 15, fk = (l >> 4) << 3;
  f32x4 acc[4];
  #pragma unroll
  for (int n = 0; n < 4; ++n) acc[n] = (f32x4){0.f,0.f,0.f,0.f};

  const ushort* Aptr = Ab + (size_t)(mt*64 + lr)*lda + lc;
  const ushort* Bptr = Bb + (size_t)(nt*64 + lr)*ldb + lc;
  for (int k0 = 0; k0 < K; k0 += 32){
    uint4 av = *reinterpret_cast<const uint4*>(Aptr + k0);
    uint4 bv = *reinterpret_cast<const uint4*>(Bptr + k0);
    __syncthreads();
    *reinterpret_cast<uint4*>(&As[lr][lc]) = av;
    *reinterpret_cast<uint4*>(&Bs[lr][lc]) = bv;
    __syncthreads();
    bf16x8 af = *reinterpret_cast<const bf16x8*>(&As[w*16 + fr][fk]);
    #pragma unroll
    for (int n = 0; n < 4; ++n){
      bf16x8 bf = *reinterpret_cast<const bf16x8*>(&Bs[n*16 + fr][fk]);
      acc[n] = __builtin_amdgcn_mfma_f32_16x16x32_bf16(af, bf, acc[n], 0, 0, 0);
    }
  }
  int fq = l >> 4;
  #pragma unroll
  for (int n = 0; n < 4; ++n){
    #pragma unroll
    for (int r = 0; r < 4; ++r){
      int row = mt*64 + w*16 + fq*4 + r;
      int col = nt*64 + n*16 + fr;
      outF[(size_t)z*sO + (size_t)row*ldo + col] = acc[n][r];
    }
  }
}

// ---------------- T_ip[b][k][n] = 0.125 * sum_c text[b,k,c]*ip[b,n,c] ----------------
__global__ __launch_bounds__(64) void tip_k(const float* __restrict__ enc, float* __restrict__ tip){
  int k = blockIdx.x, n = blockIdx.y, b = blockIdx.z;
  const float* text = enc + ((size_t)b*81 + k)*2048;
  const float* ip   = enc + ((size_t)b*81 + 77 + n)*2048;
  int l = threadIdx.x;
  float acc = 0.f;
  for (int c = l; c < 2048; c += 64) acc += text[c]*ip[c];
  for (int off = 32; off > 0; off >>= 1) acc += __shfl_down(acc, off);
  if (l == 0) tip[((size_t)b*77 + k)*4 + n] = acc * 0.125f;
}

// ---------------- softmax over 77 logits + sem = p @ T_ip ----------------
__global__ __launch_bounds__(128) void semsm_k(const float* __restrict__ logits,
    const float* __restrict__ tip, float* __restrict__ sem)
{
  int row = blockIdx.x;
  int b = row >> 12;
  int t = threadIdx.x;
  __shared__ float ls[77];
  __shared__ float ps[77];
  if (t < 77) ls[t] = logits[(size_t)row*128 + t] * 0.125f;
  __syncthreads();
  float m = -1e30f;
  for (int k = 0; k < 77; ++k) m = fmaxf(m, ls[k]);
  float s = 0.f;
  for (int k = 0; k < 77; ++k) s += __expf(ls[k]-m);
  if (t < 77) ps[t] = __expf(ls[t]-m) / s;
  __syncthreads();
  if (t < 4){
    float acc = 0.f;
    const float* tp = tip + (size_t)b*77*4 + t;
    for (int k = 0; k < 77; ++k) acc += ps[k]*tp[k*4];
    sem[(size_t)row*4 + t] = acc;
  }
}

// ---------------- MFMA fused text+ip attention ----------------
__global__ __launch_bounds__(256) void attn_mfma_k(
    const ushort* __restrict__ qb, const ushort* __restrict__ pall,
    const float* __restrict__ sem, const float* __restrict__ mask,
    ushort* __restrict__ hmid)
{
  int qt = blockIdx.x;   // 0..63
  int h  = blockIdx.y;   // 0..19
  int b  = blockIdx.z;   // 0..3
  __shared__ ushort Qs[64][72];
  __shared__ ushort Ks[96][72];
  __shared__ ushort Vt[64][104];  // V^T: [d][k]
  __shared__ ushort Ps[64][104];
  int t = threadIdx.x;
  int w = t >> 6, l = t & 63;
  const ushort* pb = pall + (size_t)b*81*5120 + h*64;

  {
    int base = b*4096 + qt*64;
    #pragma unroll
    for (int it = 0; it < 2; ++it){
      int chunk = t + it*256;
      int r = chunk >> 3, dp = (chunk & 7) << 3;
      uint4 v = *reinterpret_cast<const uint4*>(qb + (size_t)(base + r)*1280 + h*64 + dp);
      *reinterpret_cast<uint4*>(&Qs[r][dp]) = v;
    }
  }
  #pragma unroll
  for (int it = 0; it < 6; ++it){
    int chunk = t + it*256;
    int k = chunk >> 4, dp = (chunk & 15) << 2;
    ushort4 v = make_ushort4(0,0,0,0);
    if (k < 77)      v = *reinterpret_cast<const ushort4*>(pb + (size_t)k*5120 + dp);
    else if (k < 81) v = *reinterpret_cast<const ushort4*>(pb + (size_t)k*5120 + 2560 + dp);
    *reinterpret_cast<ushort4*>(&Ks[k][dp]) = v;
  }
  #pragma unroll
  for (int it = 0; it < 24; ++it){
    int idx = t + it*256;
    int k = idx >> 6, d = idx & 63;
    ushort v = 0;
    if (k < 77)      v = pb[(size_t)k*5120 + 1280 + d];
    else if (k < 81) v = pb[(size_t)k*5120 + 3840 + d];
    Vt[d][k] = v;
  }
  __syncthreads();

  int fr = l & 15, fq = l >> 4, fkb = fq << 3;
  int c = fr;

  f32x4 s[6];
  #pragma unroll
  for (int n = 0; n < 6; ++n) s[n] = (f32x4){0.f,0.f,0.f,0.f};
  #pragma unroll
  for (int ks = 0; ks < 2; ++ks){
    bf16x8 aq = *reinterpret_cast<const bf16x8*>(&Qs[w*16 + fr][ks*32 + fkb]);
    #pragma unroll
    for (int n = 0; n < 6; ++n){
      bf16x8 bk = *reinterpret_cast<const bf16x8*>(&Ks[n*16 + fr][ks*32 + fkb]);
      s[n] = __builtin_amdgcn_mfma_f32_16x16x32_bf16(aq, bk, s[n], 0, 0, 0);
    }
  }

  int rowbase = qt*64 + w*16 + (fq << 2);
  #pragma unroll
  for (int r = 0; r < 4; ++r){
    float lg[6];
    #pragma unroll
    for (int n = 0; n < 6; ++n) lg[n] = s[n][r]*0.125f;

    float mt = fmaxf(fmaxf(lg[0],lg[1]), fmaxf(lg[2],lg[3]));
    if (c < 13) mt = fmaxf(mt, lg[4]);
    #pragma unroll
    for (int off = 1; off < 16; off <<= 1) mt = fmaxf(mt, __shfl_xor(mt, off));
    float st = __expf(lg[0]-mt) + __expf(lg[1]-mt) + __expf(lg[2]-mt) + __expf(lg[3]-mt);
    if (c < 13) st += __expf(lg[4]-mt);
    #pragma unroll
    for (int off = 1; off < 16; off <<= 1) st += __shfl_xor(st, off);
    float invst = 1.f/st;

    size_t qrow = (size_t)b*4096 + rowbase + r;
    float f4 = -1e30f, f5 = -1e30f;
    if (c >= 13) f4 = lg[4] + 0.5f*sem[qrow*4 + (c-13)];
    if (c == 0)  f5 = lg[5] + 0.5f*sem[qrow*4 + 3];
    float m2 = fmaxf(f4, f5);
    #pragma unroll
    for (int off = 1; off < 16; off <<= 1) m2 = fmaxf(m2, __shfl_xor(m2, off));
    float si = (c >= 13 ? __expf(f4-m2) : 0.f) + (c == 0 ? __expf(f5-m2) : 0.f);
    #pragma unroll
    for (int off = 1; off < 16; off <<= 1) si += __shfl_xor(si, off);
    float pmul = mask[rowbase + r] / si;

    int prow = w*16 + (fq << 2) + r;
    #pragma unroll
    for (int n = 0; n < 4; ++n) Ps[prow][n*16 + c] = f2b(__expf(lg[n]-mt)*invst);
    Ps[prow][64 + c] = f2b(c < 13 ? __expf(lg[4]-mt)*invst : __expf(f4-m2)*pmul);
    Ps[prow][80 + c] = f2b(c == 0 ? __expf(f5-m2)*pmul : 0.f);
  }
  __syncthreads();

  f32x4 o[4];
  #pragma unroll
  for (int df = 0; df < 4; ++df) o[df] = (f32x4){0.f,0.f,0.f,0.f};
  #pragma unroll
  for (int ks = 0; ks < 3; ++ks){
    bf16x8 ap = *reinterpret_cast<const bf16x8*>(&Ps[w*16 + fr][ks*32 + fkb]);
    #pragma unroll
    for (int df = 0; df < 4; ++df){
      bf16x8 bv = *reinterpret_cast<const bf16x8*>(&Vt[df*16 + fr][ks*32 + fkb]);
      o[df] = __builtin_amdgcn_mfma_f32_16x16x32_bf16(ap, bv, o[df], 0, 0, 0);
    }
  }
  #pragma unroll
  for (int df = 0; df < 4; ++df)
    #pragma unroll
    for (int r = 0; r < 4; ++r)
      hmid[((size_t)b*4096 + rowbase + r)*1280 + h*64 + df*16 + c] = f2b(o[df][r]);
}

extern "C" void kernel_launch(void* const* d_in, const int* in_sizes, int n_in,
                              void* d_out, int out_size, void* d_ws, size_t ws_size,
                              hipStream_t stream)
{
  (void)in_sizes; (void)n_in; (void)out_size; (void)ws_size;
  const float* hs   = (const float*)d_in[0];
  const float* enc  = (const float*)d_in[1];
  const float* mask = (const float*)d_in[2];
  const float* Wq   = (const float*)d_in[3];
  const float* Wk   = (const float*)d_in[4];
  const float* Wv   = (const float*)d_in[5];
  const float* Wkip = (const float*)d_in[6];
  const float* Wvip = (const float*)d_in[7];
  const float* Wout = (const float*)d_in[8];
  const float* bout = (const float*)d_in[9];
  float* out = (float*)d_out;
  char* ws = (char*)d_ws;

  size_t off = 0;
  auto alloc = [&](size_t bytes)->char*{
    char* p = ws + off; off += (bytes + 255) & ~(size_t)255; return p;
  };
  ushort* hs_bf   = (ushort*)alloc(16384ull*1280*2);   // reused as hmid
  ushort* q_bf    = (ushort*)alloc(16384ull*1280*2);
  ushort* enc_bf  = (ushort*)alloc(384ull*2048*2);
  ushort* wqt     = (ushort*)alloc(1280ull*1280*2);
  ushort* woutt   = (ushort*)alloc(1280ull*1280*2);
  ushort* wcat    = (ushort*)alloc(5120ull*2048*2);
  ushort* pall    = (ushort*)alloc(384ull*5120*2);
  float*  logits  = (float*)alloc(16384ull*128*4);
  float*  tip     = (float*)alloc(4ull*77*4*4);
  float*  semb    = (float*)alloc(16384ull*4*4);
  ushort* hmid_bf = hs_bf;

  cvt_bf16_k<<<20480, 256, 0, stream>>>(hs, hs_bf, 16384*1280/4);
  cvt_enc_k<<<768, 256, 0, stream>>>(enc, enc_bf);
  transpose_bf16_k<<<dim3(40,40), 256, 0, stream>>>(Wq,   wqt,   1280, 1280);
  transpose_bf16_k<<<dim3(40,40), 256, 0, stream>>>(Wout, woutt, 1280, 1280);
  transpose_bf16_k<<<dim3(40,64), 256, 0, stream>>>(Wk,   wcat + 0ull*1280*2048, 2048, 1280);
  transpose_bf16_k<<<dim3(40,64), 256, 0, stream>>>(Wv,   wcat + 1ull*1280*2048, 2048, 1280);
  transpose_bf16_k<<<dim3(40,64), 256, 0, stream>>>(Wkip, wcat + 2ull*1280*2048, 2048, 1280);
  transpose_bf16_k<<<dim3(40,64), 256, 0, stream>>>(Wvip, wcat + 3ull*1280*2048, 2048, 1280);

  // encoder projections: pall[384][5120] = enc_bf @ wcat^T  (bf16 out)
  gemm128<0><<<dim3((384/128)*(5120/128)), 256, 0, stream>>>(enc_bf, wcat, 384, 5120, 2048,
      2048, 2048, 5120, nullptr, pall, nullptr, nullptr);

  // q = hs @ Wq (bf16 out)
  gemm128<0><<<dim3((16384/128)*(1280/128)), 256, 0, stream>>>(hs_bf, wqt, 16384, 1280, 1280,
      1280, 1280, 1280, nullptr, q_bf, nullptr, nullptr);

  tip_k<<<dim3(77,4,4), 64, 0, stream>>>(enc, tip);

  // logits[b][4096][128] = q @ k_text^T  (batched; N padded to 128)
  gemm64<<<dim3((4096/64)*(128/64),1,4), 256, 0, stream>>>(q_bf, pall, 4096, 128, 1280,
      1280, 5120, 128, 4096ll*1280, 81ll*5120, 4096ll*128, logits);

  semsm_k<<<16384, 128, 0, stream>>>(logits, tip, semb);

  attn_mfma_k<<<dim3(64,20,4), 256, 0, stream>>>(q_bf, pall, semb, mask, hmid_bf);

  // out = hmid @ Wout + bout + residual
  gemm128<1><<<dim3((16384/128)*(1280/128)), 256, 0, stream>>>(hmid_bf, woutt, 16384, 1280, 1280,
      1280, 1280, 1280, out, nullptr, bout, hs);
}